// Round 9
// baseline (773.322 us; speedup 1.0000x reference)
//
#include <hip/hip_runtime.h>
#include <cstdint>
#include <cstddef>

#define B_ROWS 8192
#define D_DIM  1024
#define H_DIM  4096
#define O_DIM  1024
#define E_NUM  3
#define K2     (2 * H_DIM)          // per-slot K in expert GEMM2
#define MT256  34                   // worst-case 256-row m-tiles: 32 + 2 (256-pad per bucket)
#define SLOT_MAX (MT256 * 256)

typedef __attribute__((ext_vector_type(4))) float f4;
typedef __attribute__((ext_vector_type(8))) _Float16 half8;

__device__ __forceinline__ unsigned short f2h_bits(float f) {
  _Float16 h = (_Float16)f;
  return __builtin_bit_cast(unsigned short, h);
}

// async global->LDS, 16B per lane. LDS dest = wave-uniform base + lane*16.
__device__ __forceinline__ void async16(const void* g, void* l) {
  __builtin_amdgcn_global_load_lds(
      (const __attribute__((address_space(1))) unsigned int*)g,
      (__attribute__((address_space(3))) unsigned int*)l, 16, 0, 0);
}

// ---------------- cast x (fp32 -> f16), 8 elems/thread ----------------
__global__ __launch_bounds__(256) void k_cast_x(const float* __restrict__ in,
                                                unsigned short* __restrict__ out) {
  size_t i = (size_t)blockIdx.x * 256 + threadIdx.x;
  const f4* p = (const f4*)in;
  f4 a = p[2 * i], b = p[2 * i + 1];
  half8 h;
#pragma unroll
  for (int j = 0; j < 4; ++j) { h[j] = (_Float16)a[j]; h[4 + j] = (_Float16)b[j]; }
  *(half8*)(out + 8 * i) = h;
}

// ------------- transpose + cast: in[e][R][C] f32 -> out[e][C][R] f16 -------------
__global__ __launch_bounds__(256) void k_transpose_cast(const float* __restrict__ in,
                                                        unsigned short* __restrict__ out,
                                                        int R, int C) {
  __shared__ float tile[32][33];
  const size_t eoff = (size_t)blockIdx.z * R * C;
  const float* I = in + eoff;
  unsigned short* O = out + eoff;
  int c0 = blockIdx.x * 32, r0 = blockIdx.y * 32;
  int tx = threadIdx.x & 31, ty = threadIdx.x >> 5;
#pragma unroll
  for (int i = 0; i < 4; ++i)
    tile[ty + 8 * i][tx] = I[(size_t)(r0 + ty + 8 * i) * C + c0 + tx];
  __syncthreads();
#pragma unroll
  for (int i = 0; i < 4; ++i)
    O[(size_t)(c0 + ty + 8 * i) * R + r0 + tx] = f2h_bits(tile[tx][ty + 8 * i]);
}

// ======== fused gating layers 1+2 (fp32), 32-row stripe per block ========
// Phase A: g1t[32][256] = relu(x[32x1024] @ gw1 + gb1)  -> LDS
// Phase B: h2[32][128]  = relu(g1t      @ gw2 + gb2)    -> global
// Per-element fma chains are BITWISE IDENTICAL to the unfused k_gemm_f32
// pair (k0 outer/kk inner ascending, staging = pure copy, same relu+bias),
// so h2 is bit-exact and top-k routing cannot drift. x is read once
// (unfused layer-1 re-read it 4x = 134 MB); g1 never touches HBM.
__global__ __launch_bounds__(512) void k_gate12(const float* __restrict__ x,
                                                const float* __restrict__ gw1,
                                                const float* __restrict__ gb1,
                                                const float* __restrict__ gw2,
                                                const float* __restrict__ gb2,
                                                float* __restrict__ h2out) {
  __shared__ float g1t[32][264];   // row stride 1056 B (16B-aligned for f4)
  __shared__ float sB[16][260];    // B panel: 16 x 256 (A) / 16 x 128 (B)
  __shared__ float sAT[16][36];    // A^T chunk: 16 k x 32 rows
  const int t = threadIdx.x;
  const int m0 = blockIdx.x * 32;

  // ---- Phase A: thread = 4 rows x 4 cols; ty=t>>6 (8 row-grps), tx=t&63 (64 col-grps)
  const int ty = t >> 6, tx = t & 63;
  float acc[4][4] = {};
  for (int k0 = 0; k0 < D_DIM; k0 += 16) {
    __syncthreads();
    {  // stage A^T: 32 rows x 16 k = 512 entries, 1 per thread
      int r = t >> 4, c = t & 15;
      sAT[c][r] = x[(size_t)(m0 + r) * D_DIM + k0 + c];
    }
#pragma unroll
    for (int i = 0; i < 8; ++i) {  // stage B: 16 x 256 = 4096 entries
      int idx = t + i * 512;
      int rb = idx >> 8, cb = idx & 255;
      sB[rb][cb] = gw1[(size_t)(k0 + rb) * 256 + cb];
    }
    __syncthreads();
#pragma unroll
    for (int kk = 0; kk < 16; ++kk) {
      f4 av = *(const f4*)&sAT[kk][ty * 4];
      f4 bv = *(const f4*)&sB[kk][tx * 4];
#pragma unroll
      for (int i = 0; i < 4; ++i)
#pragma unroll
        for (int j = 0; j < 4; ++j)
          acc[i][j] = fmaf(av[i], bv[j], acc[i][j]);
    }
  }
  __syncthreads();
#pragma unroll
  for (int i = 0; i < 4; ++i) {
    f4 v;
#pragma unroll
    for (int j = 0; j < 4; ++j)
      v[j] = fmaxf(acc[i][j] + gb1[tx * 4 + j], 0.f);
    *(f4*)&g1t[ty * 4 + i][tx * 4] = v;
  }

  // ---- Phase B: thread = 2 rows x 4 cols; ty2=t>>5 (16 row-grps), tx2=t&31 (32 col-grps)
  const int ty2 = t >> 5, tx2 = t & 31;
  float acc2[2][4] = {};
  for (int k0 = 0; k0 < 256; k0 += 16) {
    __syncthreads();
#pragma unroll
    for (int i = 0; i < 4; ++i) {  // stage gw2 chunk: 16 x 128 = 2048 entries
      int idx = t + i * 512;
      int rb = idx >> 7, cb = idx & 127;
      sB[rb][cb] = gw2[(size_t)(k0 + rb) * 128 + cb];
    }
    __syncthreads();
#pragma unroll
    for (int kk = 0; kk < 16; ++kk) {
      float a0 = g1t[ty2 * 2 + 0][k0 + kk];
      float a1 = g1t[ty2 * 2 + 1][k0 + kk];
      f4 bv = *(const f4*)&sB[kk][tx2 * 4];
#pragma unroll
      for (int j = 0; j < 4; ++j) {
        acc2[0][j] = fmaf(a0, bv[j], acc2[0][j]);
        acc2[1][j] = fmaf(a1, bv[j], acc2[1][j]);
      }
    }
  }
#pragma unroll
  for (int i = 0; i < 2; ++i) {
    int row = m0 + ty2 * 2 + i;
    f4 v;
#pragma unroll
    for (int j = 0; j < 4; ++j)
      v[j] = fmaxf(acc2[i][j] + gb2[tx2 * 4 + j], 0.f);
    *(f4*)&h2out[(size_t)row * 128 + tx2 * 4] = v;
  }
}

// ------------- gating layer 3 + softmax + top-2 + renorm + bucket id -------------
__global__ __launch_bounds__(256) void k_gate_topk(const float* __restrict__ h2,
                                                   const float* __restrict__ gw3,
                                                   const float* __restrict__ gb3,
                                                   float* __restrict__ gates,
                                                   float* __restrict__ combine,
                                                   int* __restrict__ bucket) {
  const int lane = threadIdx.x & 63;
  const int row = blockIdx.x * 4 + (threadIdx.x >> 6);
  const float* h = h2 + (size_t)row * 128;
  float h0 = h[lane], h1 = h[lane + 64];
  float l0 = h0 * gw3[lane * 3 + 0] + h1 * gw3[(lane + 64) * 3 + 0];
  float l1 = h0 * gw3[lane * 3 + 1] + h1 * gw3[(lane + 64) * 3 + 1];
  float l2 = h0 * gw3[lane * 3 + 2] + h1 * gw3[(lane + 64) * 3 + 2];
#pragma unroll
  for (int off = 32; off > 0; off >>= 1) {
    l0 += __shfl_down(l0, off);
    l1 += __shfl_down(l1, off);
    l2 += __shfl_down(l2, off);
  }
  if (lane == 0) {
    float g0 = l0 + gb3[0], g1v = l1 + gb3[1], g2v = l2 + gb3[2];
    float mx = fmaxf(g0, fmaxf(g1v, g2v));
    float e0 = expf(g0 - mx), e1 = expf(g1v - mx), e2 = expf(g2v - mx);
    float inv = 1.f / (e0 + e1 + e2);
    float p0 = e0 * inv, p1 = e1 * inv, p2 = e2 * inv;
    gates[row * 3 + 0] = p0; gates[row * 3 + 1] = p1; gates[row * 3 + 2] = p2;
    // exclude argmin; '<=' so ties exclude the HIGHER index (lax.top_k tie rule)
    int amin = 0; float pm = p0;
    if (p1 <= pm) { pm = p1; amin = 1; }
    if (p2 <= pm) { pm = p2; amin = 2; }
    float denom = (p0 + p1 + p2) - pm;
    combine[row * 3 + 0] = (amin == 0) ? 0.f : p0 / denom;
    combine[row * 3 + 1] = (amin == 1) ? 0.f : p1 / denom;
    combine[row * 3 + 2] = (amin == 2) ? 0.f : p2 / denom;
    bucket[row] = amin;  // bucket = excluded expert
  }
}

// ------------- routing: count / bases / scatter (ballot-aggregated atomics) -------------
__global__ __launch_bounds__(256) void k_count(const int* __restrict__ bucket,
                                               int* __restrict__ cnt) {
  int row = blockIdx.x * 256 + threadIdx.x;
  int b = bucket[row];
  int lane = threadIdx.x & 63;
#pragma unroll
  for (int bid = 0; bid < 3; ++bid) {
    unsigned long long m = __ballot(b == bid);
    if (m && b == bid) {
      int prefix = __popcll(m & ((1ull << lane) - 1));
      if (prefix == 0) atomicAdd(&cnt[bid], __popcll(m));
    }
  }
}

// meta[0..3] = tile-base prefix in 256-row tiles (tiles_b = ceil(cnt_b/256)); zeroes cnt2.
__global__ void k_meta(const int* __restrict__ cnt, int* __restrict__ meta,
                       int* __restrict__ cnt2) {
  int t0 = (cnt[0] + 255) >> 8;
  int t1 = (cnt[1] + 255) >> 8;
  int t2 = (cnt[2] + 255) >> 8;
  meta[0] = 0; meta[1] = t0; meta[2] = t0 + t1; meta[3] = t0 + t1 + t2;
  cnt2[0] = 0; cnt2[1] = 0; cnt2[2] = 0;
}

__global__ __launch_bounds__(256) void k_scatter(const int* __restrict__ bucket,
                                                 const int* __restrict__ meta,
                                                 int* __restrict__ cnt2,
                                                 int* __restrict__ sorted) {
  int row = blockIdx.x * 256 + threadIdx.x;
  int b = bucket[row];
  int lane = threadIdx.x & 63;
#pragma unroll
  for (int bid = 0; bid < 3; ++bid) {
    unsigned long long m = __ballot(b == bid);
    if (m) {
      int cntm = __popcll(m);
      int leader = __ffsll((unsigned long long)m) - 1;
      int base = 0;
      if (lane == leader) base = atomicAdd(&cnt2[bid], cntm);
      base = __shfl(base, leader);
      if (b == bid) {
        int prefix = __popcll(m & ((1ull << lane) - 1));
        sorted[meta[bid] * 256 + base + prefix] = row;
      }
    }
  }
}

// experts for bucket b (b = excluded expert)
__device__ __forceinline__ void bucket_experts(int b, int& ea, int& eb) {
  ea = (b == 0) ? 1 : 0;
  eb = (b == 2) ? 1 : 2;
}

// ==================== 8-phase 256x256 schedule machinery (T3+T4+T5) ====================
// 512 threads = 8 waves (2M x 4N), wave tile 128x64, BK=64, 2 K-tiles/iteration.
// LDS: A dbuf 2x32KB + B dbuf 2x32KB = 128KB, XOR chunk swizzle.
// vmcnt(4) at end-P4 / end-P8 keep prefetch loads in flight across barriers.

#define BAR8()  do { __builtin_amdgcn_s_barrier(); __builtin_amdgcn_sched_barrier(0); } while (0)
#define LGKM0() do { asm volatile("s_waitcnt lgkmcnt(0)" ::: "memory"); __builtin_amdgcn_sched_barrier(0); } while (0)
#define VMW(n)  do { asm volatile("s_waitcnt vmcnt(" #n ")" ::: "memory"); __builtin_amdgcn_sched_barrier(0); } while (0)

#define STG_A(buf, h, kt) do { \
    async16(aptr[(h) * 2 + 0] + (size_t)(kt) * 64, smem + (buf) * 32768 + (h) * 16384 + t * 16); \
    async16(aptr[(h) * 2 + 1] + (size_t)(kt) * 64, smem + (buf) * 32768 + (h) * 16384 + 8192 + t * 16); \
  } while (0)
#define STG_B(buf, h, kt) do { \
    async16(bptr[(h) * 2 + 0] + (size_t)(kt) * 64, smem + 65536 + (buf) * 32768 + (h) * 16384 + t * 16); \
    async16(bptr[(h) * 2 + 1] + (size_t)(kt) * 64, smem + 65536 + (buf) * 32768 + (h) * 16384 + 8192 + t * 16); \
  } while (0)
#define LDA8(buf, mh) do { \
    _Pragma("unroll") \
    for (int mf = 0; mf < 4; ++mf) { \
      fa[mf][0] = *(const half8*)(smem + (buf) * 32768 + baseA + (mh) * 8192 + mf * 2048 + ck0); \
      fa[mf][1] = *(const half8*)(smem + (buf) * 32768 + baseA + (mh) * 8192 + mf * 2048 + ck1); \
    } } while (0)
#define LDB8(buf, nh) do { \
    _Pragma("unroll") \
    for (int nf2 = 0; nf2 < 2; ++nf2) { \
      fb[(nh) * 2 + nf2][0] = *(const half8*)(smem + (buf) * 32768 + baseB + ((nh) * 2 + nf2) * 2048 + ck0); \
      fb[(nh) * 2 + nf2][1] = *(const half8*)(smem + (buf) * 32768 + baseB + ((nh) * 2 + nf2) * 2048 + ck1); \
    } } while (0)
#define MM8(mh, nh) do { \
    _Pragma("unroll") \
    for (int mf = 0; mf < 4; ++mf) { \
      _Pragma("unroll") \
      for (int nf2 = 0; nf2 < 2; ++nf2) { \
        acc[(mh) * 4 + mf][(nh) * 2 + nf2] = __builtin_amdgcn_mfma_f32_16x16x32_f16( \
            fa[mf][0], fb[(nh) * 2 + nf2][0], acc[(mh) * 4 + mf][(nh) * 2 + nf2], 0, 0, 0); \
        acc[(mh) * 4 + mf][(nh) * 2 + nf2] = __builtin_amdgcn_mfma_f32_16x16x32_f16( \
            fa[mf][1], fb[(nh) * 2 + nf2][1], acc[(mh) * 4 + mf][(nh) * 2 + nf2], 0, 0, 0); \
      } } } while (0)

// Main pipelined K-loop: NITER iterations of 2 K-tiles; last kt index = 2*NITER-1.
#define KLOOP8(NITER, LASTKT) \
  _Pragma("unroll 1") \
  for (int it = 0; it < (NITER) - 1; ++it) { \
    const int kt = 2 * it; \
    LDA8(0, 0); LDB8(0, 0); STG_A(1, 0, kt + 1); \
    BAR8(); LGKM0(); \
    __builtin_amdgcn_s_setprio(1); MM8(0, 0); __builtin_amdgcn_s_setprio(0); \
    BAR8(); \
    LDB8(0, 1); STG_A(1, 1, kt + 1); \
    BAR8(); LGKM0(); \
    __builtin_amdgcn_s_setprio(1); MM8(0, 1); __builtin_amdgcn_s_setprio(0); \
    BAR8(); \
    LDA8(0, 1); STG_B(0, 0, kt + 2); \
    BAR8(); LGKM0(); \
    __builtin_amdgcn_s_setprio(1); MM8(1, 0); __builtin_amdgcn_s_setprio(0); \
    BAR8(); \
    STG_A(0, 0, kt + 2); \
    BAR8(); LGKM0(); \
    __builtin_amdgcn_s_setprio(1); MM8(1, 1); __builtin_amdgcn_s_setprio(0); \
    VMW(4); BAR8(); \
    LDA8(1, 0); LDB8(1, 0); STG_A(0, 1, kt + 2); \
    BAR8(); LGKM0(); \
    __builtin_amdgcn_s_setprio(1); MM8(0, 0); __builtin_amdgcn_s_setprio(0); \
    BAR8(); \
    LDB8(1, 1); STG_B(0, 1, kt + 2); \
    BAR8(); LGKM0(); \
    __builtin_amdgcn_s_setprio(1); MM8(0, 1); __builtin_amdgcn_s_setprio(0); \
    BAR8(); \
    LDA8(1, 1); STG_B(1, 0, kt + 3); \
    BAR8(); LGKM0(); \
    __builtin_amdgcn_s_setprio(1); MM8(1, 0); __builtin_amdgcn_s_setprio(0); \
    BAR8(); \
    STG_B(1, 1, kt + 3); \
    BAR8(); LGKM0(); \
    __builtin_amdgcn_s_setprio(1); MM8(1, 1); __builtin_amdgcn_s_setprio(0); \
    VMW(4); BAR8(); \
  } \
  { /* epilogue iteration: buf0 = kt LASTKT-1, stage buf1.A <- LASTKT, then buf1 */ \
    LDA8(0, 0); LDB8(0, 0); STG_A(1, 0, LASTKT); \
    BAR8(); LGKM0(); \
    __builtin_amdgcn_s_setprio(1); MM8(0, 0); __builtin_amdgcn_s_setprio(0); \
    BAR8(); \
    LDB8(0, 1); STG_A(1, 1, LASTKT); \
    BAR8(); LGKM0(); \
    __builtin_amdgcn_s_setprio(1); MM8(0, 1); __builtin_amdgcn_s_setprio(0); \
    BAR8(); \
    LDA8(0, 1); \
    BAR8(); LGKM0(); \
    __builtin_amdgcn_s_setprio(1); MM8(1, 0); __builtin_amdgcn_s_setprio(0); \
    BAR8(); \
    BAR8(); LGKM0(); \
    __builtin_amdgcn_s_setprio(1); MM8(1, 1); __builtin_amdgcn_s_setprio(0); \
    VMW(0); BAR8(); \
    LDA8(1, 0); LDB8(1, 0); MM8(0, 0); \
    LDB8(1, 1); MM8(0, 1); \
    LDA8(1, 1); MM8(1, 0); \
    MM8(1, 1); \
  }

// ==================== expert GEMM1 (routed), 8-phase 256x256 ====================
// ehs[slot][z*H + col] = f16(c * relu(x[r] @ w1_e + eb1_e))
__global__ __launch_bounds__(512, 2) void k_expert_h8(const unsigned short* __restrict__ Xh,
                                                      const unsigned short* __restrict__ W1T,
                                                      const float* __restrict__ combine,
                                                      const float* __restrict__ eb1,
                                                      const int* __restrict__ sorted,
                                                      const int* __restrict__ meta,
                                                      unsigned short* __restrict__ EHS) {
  constexpr int K = D_DIM;  // 1024, 16 K-tiles of 64, 8 iterations
  const int mt = blockIdx.x;
  const int tb1 = meta[1], tb2 = meta[2], tb3 = meta[3];
  if (mt >= tb3) return;
  const int b = (mt >= tb2) ? 2 : (mt >= tb1) ? 1 : 0;
  int ea, ebx; bucket_experts(b, ea, ebx);
  const int z = blockIdx.z;
  const int e = z ? ebx : ea;
  const int slot0 = mt * 256;
  const int n0 = blockIdx.y * 256;

  __shared__ __align__(16) char smem[131072];
  __shared__ float sC[256];
  const int t = threadIdx.x;
  if (t < 256) {
    int r = sorted[slot0 + t];
    sC[t] = (r < 0) ? 0.f : combine[(size_t)r * 3 + e];
  }

  // staging: 4 rows per thread (R = (t>>3) + i*64), pre-swizzled global chunk
  const int jrow = t >> 3;
  const int j = (t & 7) ^ (jrow & 7);
  const unsigned short* aptr[4];
  const unsigned short* bptr[4];
#pragma unroll
  for (int i = 0; i < 4; ++i) {
    int R = jrow + i * 64;
    int r = sorted[slot0 + R];
    int rr = (r < 0) ? 0 : r;
    aptr[i] = Xh + (size_t)rr * K + j * 8;
    bptr[i] = W1T + (size_t)e * H_DIM * K + (size_t)(n0 + R) * K + j * 8;
  }
  const int lane = t & 63;
  const int wid = t >> 6;
  const int wm = wid >> 2, wn = wid & 3;
  const int quad = lane >> 4, l16 = lane & 15;
  const int ck0 = ((quad) ^ (l16 & 7)) * 16;        // k-slice 0 chunk (swizzled)
  const int ck1 = ((4 + quad) ^ (l16 & 7)) * 16;    // k-slice 1 chunk
  const int baseA = (wm * 128 + l16) * 128;
  const int baseB = 65536 + (wn * 64 + l16) * 128;

  f4 acc[8][4] = {};
  half8 fa[4][2], fb[4][2];

  // prologue: buf0 <- kt0 (A+B), buf1.B <- kt1 (buf1.A staged by it0's P1/P2)
  STG_A(0, 0, 0); STG_A(0, 1, 0); STG_B(0, 0, 0); STG_B(0, 1, 0);
  STG_B(1, 0, 1); STG_B(1, 1, 1);
  VMW(4); BAR8();

  KLOOP8(8, 15)

  const float* bias = eb1 + (size_t)e * H_DIM;
#pragma unroll
  for (int nf = 0; nf < 4; ++nf) {
    int col = n0 + wn * 64 + nf * 16 + l16;
    float bb = bias[col];
#pragma unroll
    for (int mf = 0; mf < 8; ++mf) {
#pragma unroll
      for (int r = 0; r < 4; ++r) {
        int rloc = wm * 128 + mf * 16 + quad * 4 + r;
        float v = fmaxf(acc[mf][nf][r] + bb, 0.f) * sC[rloc];
        EHS[(size_t)(slot0 + rloc) * K2 + (size_t)z * H_DIM + col] = f2h_bits(v);
      }
    }
  }
}

// ======= expert GEMM2 (routed, split-K by expert half), 8-phase 256x256 =======
// OUT += ehs[slot, half] @ w2_e   (hz=0 adds both bias terms; OUT pre-zeroed;
// f32 atomicAdds commute -> deterministic; split-2 = 17M atomics, r3-validated).
__global__ __launch_bounds__(512, 2) void k_expert_o8(const unsigned short* __restrict__ EHS,
                                                      const unsigned short* __restrict__ W2T,
                                                      const float* __restrict__ combine,
                                                      const float* __restrict__ eb2,
                                                      const int* __restrict__ sorted,
                                                      const int* __restrict__ meta,
                                                      float* __restrict__ OUT) {
  const int mt = blockIdx.x;
  const int tb1 = meta[1], tb2 = meta[2], tb3 = meta[3];
  if (mt >= tb3) return;
  const int b = (mt >= tb2) ? 2 : (mt >= tb1) ? 1 : 0;
  int ea, ebx; bucket_experts(b, ea, ebx);
  const int hz = blockIdx.z;
  const int e = hz ? ebx : ea;
  const int slot0 = mt * 256;
  const int n0 = blockIdx.y * 256;

  __shared__ __align__(16) char smem[131072];
  __shared__ int sRow[256];
  __shared__ float sCa[256], sCb[256];
  const int t = threadIdx.x;
  if (t < 256) {
    int r = sorted[slot0 + t];
    sRow[t] = r;
    int rr = (r < 0) ? 0 : r;
    sCa[t] = combine[(size_t)rr * 3 + ea];
    sCb[t] = combine[(size_t)rr * 3 + ebx];
  }

  // staging: 4 rows per thread (R = (t>>3) + i*64), pre-swizzled global chunk
  const int jrow = t >> 3;
  const int j = (t & 7) ^ (jrow & 7);
  const unsigned short* aptr[4];
  const unsigned short* bptr[4];
#pragma unroll
  for (int i = 0; i < 4; ++i) {
    int R = jrow + i * 64;
    aptr[i] = EHS + (size_t)(slot0 + R) * K2 + (size_t)hz * H_DIM + j * 8;
    bptr[i] = W2T + (size_t)e * O_DIM * H_DIM + (size_t)(n0 + R) * H_DIM + j * 8;
  }
  const int lane = t & 63;
  const int wid = t >> 6;
  const int wm = wid >> 2, wn = wid & 3;
  const int quad = lane >> 4, l16 = lane & 15;
  const int ck0 = ((quad) ^ (l16 & 7)) * 16;
  const int ck1 = ((4 + quad) ^ (l16 & 7)) * 16;
  const int baseA = (wm * 128 + l16) * 128;
  const int baseB = 65536 + (wn * 64 + l16) * 128;

  f4 acc[8][4] = {};
  half8 fa[4][2], fb[4][2];

  // prologue
  STG_A(0, 0, 0); STG_A(0, 1, 0); STG_B(0, 0, 0); STG_B(0, 1, 0);
  STG_B(1, 0, 1); STG_B(1, 1, 1);
  VMW(4); BAR8();

  // K = 4096 per half: 64 K-tiles of 64 -> 32 iterations, last kt = 63
  KLOOP8(32, 63)

#pragma unroll
  for (int nf = 0; nf < 4; ++nf) {
    int col = n0 + wn * 64 + nf * 16 + l16;
    float ba = eb2[(size_t)ea * O_DIM + col];
    float bb = eb2[(size_t)ebx * O_DIM + col];
#pragma unroll
    for (int mf = 0; mf < 8; ++mf) {
#pragma unroll
      for (int r = 0; r < 4; ++r) {
        int rloc = wm * 128 + mf * 16 + quad * 4 + r;
        int rowg = sRow[rloc];
        if (rowg >= 0) {
          float v = acc[mf][nf][r];
          if (hz == 0) v += sCa[rloc] * ba + sCb[rloc] * bb;
          atomicAdd(&OUT[(size_t)rowg * O_DIM + col], v);
        }
      }
    }
  }
}

extern "C" void kernel_launch(void* const* d_in, const int* in_sizes, int n_in,
                              void* d_out, int out_size, void* d_ws, size_t ws_size,
                              hipStream_t stream) {
  const float* x   = (const float*)d_in[0];
  const float* gw1 = (const float*)d_in[1];
  const float* gb1 = (const float*)d_in[2];
  const float* gw2 = (const float*)d_in[3];
  const float* gb2 = (const float*)d_in[4];
  const float* gw3 = (const float*)d_in[5];
  const float* gb3 = (const float*)d_in[6];
  const float* ew1 = (const float*)d_in[7];
  const float* eb1 = (const float*)d_in[8];
  const float* ew2 = (const float*)d_in[9];
  const float* eb2 = (const float*)d_in[10];
  float* out = (float*)d_out;
  float* gates = out + (size_t)B_ROWS * O_DIM;

  char* ws = (char*)d_ws;
  size_t off = 0;
  auto take = [&](size_t bytes) -> char* {
    char* p = ws + off;
    off += (bytes + 255) & ~(size_t)255;
    return p;
  };
  unsigned short* xh  = (unsigned short*)take((size_t)B_ROWS * D_DIM * 2);        // 16.8 MB
  unsigned short* w1t = (unsigned short*)take((size_t)E_NUM * H_DIM * D_DIM * 2); // 25.2 MB
  unsigned short* w2t = (unsigned short*)take((size_t)E_NUM * O_DIM * H_DIM * 2); // 25.2 MB
  float* comb   = (float*)take((size_t)B_ROWS * 3 * 4);
  float* h2     = (float*)take((size_t)B_ROWS * 128 * 4);                         // 4.2 MB
  int* bucket   = (int*)take((size_t)B_ROWS * 4);
  int* sorted   = (int*)take((size_t)SLOT_MAX * 4);
  int* cnt      = (int*)take(3 * 4);
  int* cnt2     = (int*)take(3 * 4);
  int* meta     = (int*)take(4 * 4);
  unsigned short* ehs = (unsigned short*)take((size_t)SLOT_MAX * K2 * 2);         // 142.6 MB

  hipMemsetAsync(cnt, 0, 3 * 4, stream);
  hipMemsetAsync(sorted, 0xFF, (size_t)SLOT_MAX * 4, stream);  // pad slots = -1
  hipMemsetAsync(out, 0, (size_t)B_ROWS * O_DIM * 4, stream);  // accumulate base for split-K

  // precision-insensitive pre-pass: f16 casts/transposes
  k_cast_x<<<dim3(B_ROWS * D_DIM / (256 * 8)), 256, 0, stream>>>(x, xh);
  k_transpose_cast<<<dim3(H_DIM / 32, D_DIM / 32, E_NUM), 256, 0, stream>>>(ew1, w1t, D_DIM, H_DIM);
  k_transpose_cast<<<dim3(O_DIM / 32, H_DIM / 32, E_NUM), 256, 0, stream>>>(ew2, w2t, H_DIM, O_DIM);

  // gating in fp32 (top-k selection must track the fp32 reference); layers 1+2
  // fused, bitwise-identical fma chains to the unfused pair
  k_gate12<<<dim3(B_ROWS / 32), 512, 0, stream>>>(x, gw1, gb1, gw2, gb2, h2);
  k_gate_topk<<<dim3(B_ROWS / 4), 256, 0, stream>>>(h2, gw3, gb3, gates, comb, bucket);

  // routing: bucket rows by excluded expert into 256-aligned sorted segments
  k_count<<<dim3(B_ROWS / 256), 256, 0, stream>>>(bucket, cnt);
  k_meta<<<1, 1, 0, stream>>>(cnt, meta, cnt2);
  k_scatter<<<dim3(B_ROWS / 256), 256, 0, stream>>>(bucket, meta, cnt2, sorted);

  // experts in f16 MFMA, routed (2/3 of dense FLOPs), both 8-phase 256x256
  k_expert_h8<<<dim3(MT256, H_DIM / 256, 2), 512, 0, stream>>>(
      xh, w1t, comb, eb1, sorted, meta, ehs);
  k_expert_o8<<<dim3(MT256, O_DIM / 256, 2), 512, 0, stream>>>(
      ehs, w2t, comb, eb2, sorted, meta, out);
}

// Round 11
// 731.453 us; speedup vs baseline: 1.0572x; 1.0572x over previous
//
#include <hip/hip_runtime.h>
#include <cstdint>
#include <cstddef>

#define B_ROWS 8192
#define D_DIM  1024
#define H_DIM  4096
#define O_DIM  1024
#define E_NUM  3
#define K2     (2 * H_DIM)          // per-slot K in expert GEMM2
#define MT256  34                   // worst-case 256-row m-tiles: 32 + 2 (256-pad per bucket)
#define SLOT_MAX (MT256 * 256)

typedef __attribute__((ext_vector_type(4))) float f4;
typedef __attribute__((ext_vector_type(8))) _Float16 half8;

__device__ __forceinline__ unsigned short f2h_bits(float f) {
  _Float16 h = (_Float16)f;
  return __builtin_bit_cast(unsigned short, h);
}

// async global->LDS, 16B per lane. LDS dest = wave-uniform base + lane*16.
__device__ __forceinline__ void async16(const void* g, void* l) {
  __builtin_amdgcn_global_load_lds(
      (const __attribute__((address_space(1))) unsigned int*)g,
      (__attribute__((address_space(3))) unsigned int*)l, 16, 0, 0);
}

// ---------------- cast x (fp32 -> f16), 8 elems/thread ----------------
__global__ __launch_bounds__(256) void k_cast_x(const float* __restrict__ in,
                                                unsigned short* __restrict__ out) {
  size_t i = (size_t)blockIdx.x * 256 + threadIdx.x;
  const f4* p = (const f4*)in;
  f4 a = p[2 * i], b = p[2 * i + 1];
  half8 h;
#pragma unroll
  for (int j = 0; j < 4; ++j) { h[j] = (_Float16)a[j]; h[4 + j] = (_Float16)b[j]; }
  *(half8*)(out + 8 * i) = h;
}

// ------------- transpose + cast: in[e][R][C] f32 -> out[e][C][R] f16 -------------
__global__ __launch_bounds__(256) void k_transpose_cast(const float* __restrict__ in,
                                                        unsigned short* __restrict__ out,
                                                        int R, int C) {
  __shared__ float tile[32][33];
  const size_t eoff = (size_t)blockIdx.z * R * C;
  const float* I = in + eoff;
  unsigned short* O = out + eoff;
  int c0 = blockIdx.x * 32, r0 = blockIdx.y * 32;
  int tx = threadIdx.x & 31, ty = threadIdx.x >> 5;
#pragma unroll
  for (int i = 0; i < 4; ++i)
    tile[ty + 8 * i][tx] = I[(size_t)(r0 + ty + 8 * i) * C + c0 + tx];
  __syncthreads();
#pragma unroll
  for (int i = 0; i < 4; ++i)
    O[(size_t)(c0 + ty + 8 * i) * R + r0 + tx] = f2h_bits(tile[tx][ty + 8 * i]);
}

// ------------- fp32 GEMM + bias + relu (gating layers), 64x64 tile -------------
__global__ __launch_bounds__(256) void k_gemm_f32(const float* __restrict__ A,
                                                  const float* __restrict__ Bm,
                                                  const float* __restrict__ bias,
                                                  float* __restrict__ C,
                                                  int N, int K) {
  __shared__ float sAT[16][68];
  __shared__ float sB[16][68];
  const int t = threadIdx.x;
  const int tx = t & 15, ty = t >> 4;
  const int m0 = blockIdx.y * 64, n0 = blockIdx.x * 64;
  float acc[4][4] = {};
  for (int k0 = 0; k0 < K; k0 += 16) {
    __syncthreads();
#pragma unroll
    for (int i = 0; i < 4; ++i) {
      int idx = t + i * 256;
      int r = idx >> 4, c = idx & 15;
      sAT[c][r] = A[(size_t)(m0 + r) * K + (k0 + c)];
      int rb = idx >> 6, cb = idx & 63;
      sB[rb][cb] = Bm[(size_t)(k0 + rb) * N + (n0 + cb)];
    }
    __syncthreads();
#pragma unroll
    for (int kk = 0; kk < 16; ++kk) {
      f4 av = *(const f4*)&sAT[kk][ty * 4];
      f4 bv = *(const f4*)&sB[kk][tx * 4];
#pragma unroll
      for (int i = 0; i < 4; ++i)
#pragma unroll
        for (int j = 0; j < 4; ++j)
          acc[i][j] = fmaf(av[i], bv[j], acc[i][j]);
    }
  }
#pragma unroll
  for (int i = 0; i < 4; ++i) {
    int row = m0 + ty * 4 + i;
    f4 v;
#pragma unroll
    for (int j = 0; j < 4; ++j)
      v[j] = fmaxf(acc[i][j] + bias[n0 + tx * 4 + j], 0.f);
    *(f4*)&C[(size_t)row * N + n0 + tx * 4] = v;
  }
}

// ------------- gating layer 3 + softmax + top-2 + renorm + bucket id -------------
__global__ __launch_bounds__(256) void k_gate_topk(const float* __restrict__ h2,
                                                   const float* __restrict__ gw3,
                                                   const float* __restrict__ gb3,
                                                   float* __restrict__ gates,
                                                   float* __restrict__ combine,
                                                   int* __restrict__ bucket) {
  const int lane = threadIdx.x & 63;
  const int row = blockIdx.x * 4 + (threadIdx.x >> 6);
  const float* h = h2 + (size_t)row * 128;
  float h0 = h[lane], h1 = h[lane + 64];
  float l0 = h0 * gw3[lane * 3 + 0] + h1 * gw3[(lane + 64) * 3 + 0];
  float l1 = h0 * gw3[lane * 3 + 1] + h1 * gw3[(lane + 64) * 3 + 1];
  float l2 = h0 * gw3[lane * 3 + 2] + h1 * gw3[(lane + 64) * 3 + 2];
#pragma unroll
  for (int off = 32; off > 0; off >>= 1) {
    l0 += __shfl_down(l0, off);
    l1 += __shfl_down(l1, off);
    l2 += __shfl_down(l2, off);
  }
  if (lane == 0) {
    float g0 = l0 + gb3[0], g1v = l1 + gb3[1], g2v = l2 + gb3[2];
    float mx = fmaxf(g0, fmaxf(g1v, g2v));
    float e0 = expf(g0 - mx), e1 = expf(g1v - mx), e2 = expf(g2v - mx);
    float inv = 1.f / (e0 + e1 + e2);
    float p0 = e0 * inv, p1 = e1 * inv, p2 = e2 * inv;
    gates[row * 3 + 0] = p0; gates[row * 3 + 1] = p1; gates[row * 3 + 2] = p2;
    // exclude argmin; '<=' so ties exclude the HIGHER index (lax.top_k tie rule)
    int amin = 0; float pm = p0;
    if (p1 <= pm) { pm = p1; amin = 1; }
    if (p2 <= pm) { pm = p2; amin = 2; }
    float denom = (p0 + p1 + p2) - pm;
    combine[row * 3 + 0] = (amin == 0) ? 0.f : p0 / denom;
    combine[row * 3 + 1] = (amin == 1) ? 0.f : p1 / denom;
    combine[row * 3 + 2] = (amin == 2) ? 0.f : p2 / denom;
    bucket[row] = amin;  // bucket = excluded expert
  }
}

// ------------- routing: count / bases / scatter (ballot-aggregated atomics) -------------
__global__ __launch_bounds__(256) void k_count(const int* __restrict__ bucket,
                                               int* __restrict__ cnt) {
  int row = blockIdx.x * 256 + threadIdx.x;
  int b = bucket[row];
  int lane = threadIdx.x & 63;
#pragma unroll
  for (int bid = 0; bid < 3; ++bid) {
    unsigned long long m = __ballot(b == bid);
    if (m && b == bid) {
      int prefix = __popcll(m & ((1ull << lane) - 1));
      if (prefix == 0) atomicAdd(&cnt[bid], __popcll(m));
    }
  }
}

// meta[0..3] = tile-base prefix in 256-row tiles (tiles_b = ceil(cnt_b/256)); zeroes cnt2.
__global__ void k_meta(const int* __restrict__ cnt, int* __restrict__ meta,
                       int* __restrict__ cnt2) {
  int t0 = (cnt[0] + 255) >> 8;
  int t1 = (cnt[1] + 255) >> 8;
  int t2 = (cnt[2] + 255) >> 8;
  meta[0] = 0; meta[1] = t0; meta[2] = t0 + t1; meta[3] = t0 + t1 + t2;
  cnt2[0] = 0; cnt2[1] = 0; cnt2[2] = 0;
}

__global__ __launch_bounds__(256) void k_scatter(const int* __restrict__ bucket,
                                                 const int* __restrict__ meta,
                                                 int* __restrict__ cnt2,
                                                 int* __restrict__ sorted) {
  int row = blockIdx.x * 256 + threadIdx.x;
  int b = bucket[row];
  int lane = threadIdx.x & 63;
#pragma unroll
  for (int bid = 0; bid < 3; ++bid) {
    unsigned long long m = __ballot(b == bid);
    if (m) {
      int cntm = __popcll(m);
      int leader = __ffsll((unsigned long long)m) - 1;
      int base = 0;
      if (lane == leader) base = atomicAdd(&cnt2[bid], cntm);
      base = __shfl(base, leader);
      if (b == bid) {
        int prefix = __popcll(m & ((1ull << lane) - 1));
        sorted[meta[bid] * 256 + base + prefix] = row;
      }
    }
  }
}

// experts for bucket b (b = excluded expert)
__device__ __forceinline__ void bucket_experts(int b, int& ea, int& eb) {
  ea = (b == 0) ? 1 : 0;
  eb = (b == 2) ? 1 : 2;
}

// ==================== 8-phase 256x256 schedule machinery (T3+T4+T5) ====================
// 512 threads = 8 waves (2M x 4N), wave tile 128x64, BK=64, 2 K-tiles/iteration.
// LDS: A dbuf 2x32KB + B dbuf 2x32KB = 128KB, XOR chunk swizzle.
// vmcnt(4) at end-P4 / end-P8 keep prefetch loads in flight across barriers.

#define BAR8()  do { __builtin_amdgcn_s_barrier(); __builtin_amdgcn_sched_barrier(0); } while (0)
#define LGKM0() do { asm volatile("s_waitcnt lgkmcnt(0)" ::: "memory"); __builtin_amdgcn_sched_barrier(0); } while (0)
#define VMW(n)  do { asm volatile("s_waitcnt vmcnt(" #n ")" ::: "memory"); __builtin_amdgcn_sched_barrier(0); } while (0)

#define STG_A(buf, h, kt) do { \
    async16(aptr[(h) * 2 + 0] + (size_t)(kt) * 64, smem + (buf) * 32768 + (h) * 16384 + t * 16); \
    async16(aptr[(h) * 2 + 1] + (size_t)(kt) * 64, smem + (buf) * 32768 + (h) * 16384 + 8192 + t * 16); \
  } while (0)
#define STG_B(buf, h, kt) do { \
    async16(bptr[(h) * 2 + 0] + (size_t)(kt) * 64, smem + 65536 + (buf) * 32768 + (h) * 16384 + t * 16); \
    async16(bptr[(h) * 2 + 1] + (size_t)(kt) * 64, smem + 65536 + (buf) * 32768 + (h) * 16384 + 8192 + t * 16); \
  } while (0)
#define LDA8(buf, mh) do { \
    _Pragma("unroll") \
    for (int mf = 0; mf < 4; ++mf) { \
      fa[mf][0] = *(const half8*)(smem + (buf) * 32768 + baseA + (mh) * 8192 + mf * 2048 + ck0); \
      fa[mf][1] = *(const half8*)(smem + (buf) * 32768 + baseA + (mh) * 8192 + mf * 2048 + ck1); \
    } } while (0)
#define LDB8(buf, nh) do { \
    _Pragma("unroll") \
    for (int nf2 = 0; nf2 < 2; ++nf2) { \
      fb[(nh) * 2 + nf2][0] = *(const half8*)(smem + (buf) * 32768 + baseB + ((nh) * 2 + nf2) * 2048 + ck0); \
      fb[(nh) * 2 + nf2][1] = *(const half8*)(smem + (buf) * 32768 + baseB + ((nh) * 2 + nf2) * 2048 + ck1); \
    } } while (0)
#define MM8(mh, nh) do { \
    _Pragma("unroll") \
    for (int mf = 0; mf < 4; ++mf) { \
      _Pragma("unroll") \
      for (int nf2 = 0; nf2 < 2; ++nf2) { \
        acc[(mh) * 4 + mf][(nh) * 2 + nf2] = __builtin_amdgcn_mfma_f32_16x16x32_f16( \
            fa[mf][0], fb[(nh) * 2 + nf2][0], acc[(mh) * 4 + mf][(nh) * 2 + nf2], 0, 0, 0); \
        acc[(mh) * 4 + mf][(nh) * 2 + nf2] = __builtin_amdgcn_mfma_f32_16x16x32_f16( \
            fa[mf][1], fb[(nh) * 2 + nf2][1], acc[(mh) * 4 + mf][(nh) * 2 + nf2], 0, 0, 0); \
      } } } while (0)

// Main pipelined K-loop: NITER iterations of 2 K-tiles; last kt index = 2*NITER-1.
#define KLOOP8(NITER, LASTKT) \
  _Pragma("unroll 1") \
  for (int it = 0; it < (NITER) - 1; ++it) { \
    const int kt = 2 * it; \
    LDA8(0, 0); LDB8(0, 0); STG_A(1, 0, kt + 1); \
    BAR8(); LGKM0(); \
    __builtin_amdgcn_s_setprio(1); MM8(0, 0); __builtin_amdgcn_s_setprio(0); \
    BAR8(); \
    LDB8(0, 1); STG_A(1, 1, kt + 1); \
    BAR8(); LGKM0(); \
    __builtin_amdgcn_s_setprio(1); MM8(0, 1); __builtin_amdgcn_s_setprio(0); \
    BAR8(); \
    LDA8(0, 1); STG_B(0, 0, kt + 2); \
    BAR8(); LGKM0(); \
    __builtin_amdgcn_s_setprio(1); MM8(1, 0); __builtin_amdgcn_s_setprio(0); \
    BAR8(); \
    STG_A(0, 0, kt + 2); \
    BAR8(); LGKM0(); \
    __builtin_amdgcn_s_setprio(1); MM8(1, 1); __builtin_amdgcn_s_setprio(0); \
    VMW(4); BAR8(); \
    LDA8(1, 0); LDB8(1, 0); STG_A(0, 1, kt + 2); \
    BAR8(); LGKM0(); \
    __builtin_amdgcn_s_setprio(1); MM8(0, 0); __builtin_amdgcn_s_setprio(0); \
    BAR8(); \
    LDB8(1, 1); STG_B(0, 1, kt + 2); \
    BAR8(); LGKM0(); \
    __builtin_amdgcn_s_setprio(1); MM8(0, 1); __builtin_amdgcn_s_setprio(0); \
    BAR8(); \
    LDA8(1, 1); STG_B(1, 0, kt + 3); \
    BAR8(); LGKM0(); \
    __builtin_amdgcn_s_setprio(1); MM8(1, 0); __builtin_amdgcn_s_setprio(0); \
    BAR8(); \
    STG_B(1, 1, kt + 3); \
    BAR8(); LGKM0(); \
    __builtin_amdgcn_s_setprio(1); MM8(1, 1); __builtin_amdgcn_s_setprio(0); \
    VMW(4); BAR8(); \
  } \
  { /* epilogue iteration: buf0 = kt LASTKT-1, stage buf1.A <- LASTKT, then buf1 */ \
    LDA8(0, 0); LDB8(0, 0); STG_A(1, 0, LASTKT); \
    BAR8(); LGKM0(); \
    __builtin_amdgcn_s_setprio(1); MM8(0, 0); __builtin_amdgcn_s_setprio(0); \
    BAR8(); \
    LDB8(0, 1); STG_A(1, 1, LASTKT); \
    BAR8(); LGKM0(); \
    __builtin_amdgcn_s_setprio(1); MM8(0, 1); __builtin_amdgcn_s_setprio(0); \
    BAR8(); \
    LDA8(0, 1); \
    BAR8(); LGKM0(); \
    __builtin_amdgcn_s_setprio(1); MM8(1, 0); __builtin_amdgcn_s_setprio(0); \
    BAR8(); \
    BAR8(); LGKM0(); \
    __builtin_amdgcn_s_setprio(1); MM8(1, 1); __builtin_amdgcn_s_setprio(0); \
    VMW(0); BAR8(); \
    LDA8(1, 0); LDB8(1, 0); MM8(0, 0); \
    LDB8(1, 1); MM8(0, 1); \
    LDA8(1, 1); MM8(1, 0); \
    MM8(1, 1); \
  }

// ==================== expert GEMM1 (routed), 8-phase 256x256 ====================
// ehs[slot][z*H + col] = f16(c * relu(x[r] @ w1_e + eb1_e))
// Epilogue stages the C-tile through the (dead) 128KB staging LDS as f16
// [256][256], then writes EHS in contiguous 16B chunks (512B runs per 32
// lanes) instead of 32 scattered 2B stores per thread. Values bit-identical.
__global__ __launch_bounds__(512, 2) void k_expert_h8(const unsigned short* __restrict__ Xh,
                                                      const unsigned short* __restrict__ W1T,
                                                      const float* __restrict__ combine,
                                                      const float* __restrict__ eb1,
                                                      const int* __restrict__ sorted,
                                                      const int* __restrict__ meta,
                                                      unsigned short* __restrict__ EHS) {
  constexpr int K = D_DIM;  // 1024, 16 K-tiles of 64, 8 iterations
  const int mt = blockIdx.x;
  const int tb1 = meta[1], tb2 = meta[2], tb3 = meta[3];
  if (mt >= tb3) return;
  const int b = (mt >= tb2) ? 2 : (mt >= tb1) ? 1 : 0;
  int ea, ebx; bucket_experts(b, ea, ebx);
  const int z = blockIdx.z;
  const int e = z ? ebx : ea;
  const int slot0 = mt * 256;
  const int n0 = blockIdx.y * 256;

  __shared__ __align__(16) char smem[131072];
  __shared__ float sC[256];
  const int t = threadIdx.x;
  if (t < 256) {
    int r = sorted[slot0 + t];
    sC[t] = (r < 0) ? 0.f : combine[(size_t)r * 3 + e];
  }

  // staging: 4 rows per thread (R = (t>>3) + i*64), pre-swizzled global chunk
  const int jrow = t >> 3;
  const int j = (t & 7) ^ (jrow & 7);
  const unsigned short* aptr[4];
  const unsigned short* bptr[4];
#pragma unroll
  for (int i = 0; i < 4; ++i) {
    int R = jrow + i * 64;
    int r = sorted[slot0 + R];
    int rr = (r < 0) ? 0 : r;
    aptr[i] = Xh + (size_t)rr * K + j * 8;
    bptr[i] = W1T + (size_t)e * H_DIM * K + (size_t)(n0 + R) * K + j * 8;
  }
  const int lane = t & 63;
  const int wid = t >> 6;
  const int wm = wid >> 2, wn = wid & 3;
  const int quad = lane >> 4, l16 = lane & 15;
  const int ck0 = ((quad) ^ (l16 & 7)) * 16;        // k-slice 0 chunk (swizzled)
  const int ck1 = ((4 + quad) ^ (l16 & 7)) * 16;    // k-slice 1 chunk
  const int baseA = (wm * 128 + l16) * 128;
  const int baseB = 65536 + (wn * 64 + l16) * 128;

  f4 acc[8][4] = {};
  half8 fa[4][2], fb[4][2];

  // prologue: buf0 <- kt0 (A+B), buf1.B <- kt1 (buf1.A staged by it0's P1/P2)
  STG_A(0, 0, 0); STG_A(0, 1, 0); STG_B(0, 0, 0); STG_B(0, 1, 0);
  STG_B(1, 0, 1); STG_B(1, 1, 1);
  VMW(4); BAR8();

  KLOOP8(8, 15)

  // ---- coalesced epilogue: C -> LDS f16 [256][256] -> 16B global chunks ----
  __syncthreads();   // all waves done reading buf1 before smem reuse
  unsigned short* cst = (unsigned short*)smem;   // 128 KB, fits in 131072
  const float* bias = eb1 + (size_t)e * H_DIM;
#pragma unroll
  for (int nf = 0; nf < 4; ++nf) {
    int colL = wn * 64 + nf * 16 + l16;
    float bb = bias[n0 + colL];
#pragma unroll
    for (int mf = 0; mf < 8; ++mf) {
#pragma unroll
      for (int r = 0; r < 4; ++r) {
        int rloc = wm * 128 + mf * 16 + quad * 4 + r;
        float v = fmaxf(acc[mf][nf][r] + bb, 0.f) * sC[rloc];
        cst[rloc * 256 + colL] = f2h_bits(v);
      }
    }
  }
  __syncthreads();
  // 8192 chunks of 16B (256 rows x 32 chunks), 512 threads x 16
#pragma unroll
  for (int i = 0; i < 16; ++i) {
    int c = t + i * 512;
    int row = c >> 5;
    int off = (c & 31) * 8;
    *(half8*)(EHS + (size_t)(slot0 + row) * K2 + (size_t)z * H_DIM + n0 + off) =
        *(const half8*)(cst + row * 256 + off);
  }
}

// ======= expert GEMM2 (routed, split-K by expert half), 8-phase 256x256 =======
// OUT += ehs[slot, half] @ w2_e   (hz=0 adds both bias terms; OUT pre-zeroed;
// f32 atomicAdds commute -> deterministic; split-2 = 17M atomics, r3-validated).
__global__ __launch_bounds__(512, 2) void k_expert_o8(const unsigned short* __restrict__ EHS,
                                                      const unsigned short* __restrict__ W2T,
                                                      const float* __restrict__ combine,
                                                      const float* __restrict__ eb2,
                                                      const int* __restrict__ sorted,
                                                      const int* __restrict__ meta,
                                                      float* __restrict__ OUT) {
  const int mt = blockIdx.x;
  const int tb1 = meta[1], tb2 = meta[2], tb3 = meta[3];
  if (mt >= tb3) return;
  const int b = (mt >= tb2) ? 2 : (mt >= tb1) ? 1 : 0;
  int ea, ebx; bucket_experts(b, ea, ebx);
  const int hz = blockIdx.z;
  const int e = hz ? ebx : ea;
  const int slot0 = mt * 256;
  const int n0 = blockIdx.y * 256;

  __shared__ __align__(16) char smem[131072];
  __shared__ int sRow[256];
  __shared__ float sCa[256], sCb[256];
  const int t = threadIdx.x;
  if (t < 256) {
    int r = sorted[slot0 + t];
    sRow[t] = r;
    int rr = (r < 0) ? 0 : r;
    sCa[t] = combine[(size_t)rr * 3 + ea];
    sCb[t] = combine[(size_t)rr * 3 + ebx];
  }

  // staging: 4 rows per thread (R = (t>>3) + i*64), pre-swizzled global chunk
  const int jrow = t >> 3;
  const int j = (t & 7) ^ (jrow & 7);
  const unsigned short* aptr[4];
  const unsigned short* bptr[4];
#pragma unroll
  for (int i = 0; i < 4; ++i) {
    int R = jrow + i * 64;
    aptr[i] = EHS + (size_t)(slot0 + R) * K2 + (size_t)hz * H_DIM + j * 8;
    bptr[i] = W2T + (size_t)e * O_DIM * H_DIM + (size_t)(n0 + R) * H_DIM + j * 8;
  }
  const int lane = t & 63;
  const int wid = t >> 6;
  const int wm = wid >> 2, wn = wid & 3;
  const int quad = lane >> 4, l16 = lane & 15;
  const int ck0 = ((quad) ^ (l16 & 7)) * 16;
  const int ck1 = ((4 + quad) ^ (l16 & 7)) * 16;
  const int baseA = (wm * 128 + l16) * 128;
  const int baseB = 65536 + (wn * 64 + l16) * 128;

  f4 acc[8][4] = {};
  half8 fa[4][2], fb[4][2];

  // prologue
  STG_A(0, 0, 0); STG_A(0, 1, 0); STG_B(0, 0, 0); STG_B(0, 1, 0);
  STG_B(1, 0, 1); STG_B(1, 1, 1);
  VMW(4); BAR8();

  // K = 4096 per half: 64 K-tiles of 64 -> 32 iterations, last kt = 63
  KLOOP8(32, 63)

#pragma unroll
  for (int nf = 0; nf < 4; ++nf) {
    int col = n0 + wn * 64 + nf * 16 + l16;
    float ba = eb2[(size_t)ea * O_DIM + col];
    float bb = eb2[(size_t)ebx * O_DIM + col];
#pragma unroll
    for (int mf = 0; mf < 8; ++mf) {
#pragma unroll
      for (int r = 0; r < 4; ++r) {
        int rloc = wm * 128 + mf * 16 + quad * 4 + r;
        int rowg = sRow[rloc];
        if (rowg >= 0) {
          float v = acc[mf][nf][r];
          if (hz == 0) v += sCa[rloc] * ba + sCb[rloc] * bb;
          atomicAdd(&OUT[(size_t)rowg * O_DIM + col], v);
        }
      }
    }
  }
}

extern "C" void kernel_launch(void* const* d_in, const int* in_sizes, int n_in,
                              void* d_out, int out_size, void* d_ws, size_t ws_size,
                              hipStream_t stream) {
  const float* x   = (const float*)d_in[0];
  const float* gw1 = (const float*)d_in[1];
  const float* gb1 = (const float*)d_in[2];
  const float* gw2 = (const float*)d_in[3];
  const float* gb2 = (const float*)d_in[4];
  const float* gw3 = (const float*)d_in[5];
  const float* gb3 = (const float*)d_in[6];
  const float* ew1 = (const float*)d_in[7];
  const float* eb1 = (const float*)d_in[8];
  const float* ew2 = (const float*)d_in[9];
  const float* eb2 = (const float*)d_in[10];
  float* out = (float*)d_out;
  float* gates = out + (size_t)B_ROWS * O_DIM;

  char* ws = (char*)d_ws;
  size_t off = 0;
  auto take = [&](size_t bytes) -> char* {
    char* p = ws + off;
    off += (bytes + 255) & ~(size_t)255;
    return p;
  };
  unsigned short* xh  = (unsigned short*)take((size_t)B_ROWS * D_DIM * 2);        // 16.8 MB
  unsigned short* w1t = (unsigned short*)take((size_t)E_NUM * H_DIM * D_DIM * 2); // 25.2 MB
  unsigned short* w2t = (unsigned short*)take((size_t)E_NUM * O_DIM * H_DIM * 2); // 25.2 MB
  float* comb   = (float*)take((size_t)B_ROWS * 3 * 4);
  float* g1     = (float*)take((size_t)B_ROWS * 256 * 4);                         // 8.4 MB
  float* h2     = (float*)take((size_t)B_ROWS * 128 * 4);                         // 4.2 MB
  int* bucket   = (int*)take((size_t)B_ROWS * 4);
  int* sorted   = (int*)take((size_t)SLOT_MAX * 4);
  int* cnt      = (int*)take(3 * 4);
  int* cnt2     = (int*)take(3 * 4);
  int* meta     = (int*)take(4 * 4);
  unsigned short* ehs = (unsigned short*)take((size_t)SLOT_MAX * K2 * 2);         // 142.6 MB

  hipMemsetAsync(cnt, 0, 3 * 4, stream);
  hipMemsetAsync(sorted, 0xFF, (size_t)SLOT_MAX * 4, stream);  // pad slots = -1
  hipMemsetAsync(out, 0, (size_t)B_ROWS * O_DIM * 4, stream);  // accumulate base for split-K

  // precision-insensitive pre-pass: f16 casts/transposes
  k_cast_x<<<dim3(B_ROWS * D_DIM / (256 * 8)), 256, 0, stream>>>(x, xh);
  k_transpose_cast<<<dim3(H_DIM / 32, D_DIM / 32, E_NUM), 256, 0, stream>>>(ew1, w1t, D_DIM, H_DIM);
  k_transpose_cast<<<dim3(O_DIM / 32, H_DIM / 32, E_NUM), 256, 0, stream>>>(ew2, w2t, H_DIM, O_DIM);

  // gating in fp32 (top-k selection must track the fp32 reference)
  k_gemm_f32<<<dim3(256 / 64, B_ROWS / 64), 256, 0, stream>>>(x, gw1, gb1, g1, 256, D_DIM);
  k_gemm_f32<<<dim3(128 / 64, B_ROWS / 64), 256, 0, stream>>>(g1, gw2, gb2, h2, 128, 256);
  k_gate_topk<<<dim3(B_ROWS / 4), 256, 0, stream>>>(h2, gw3, gb3, gates, comb, bucket);

  // routing: bucket rows by excluded expert into 256-aligned sorted segments
  k_count<<<dim3(B_ROWS / 256), 256, 0, stream>>>(bucket, cnt);
  k_meta<<<1, 1, 0, stream>>>(cnt, meta, cnt2);
  k_scatter<<<dim3(B_ROWS / 256), 256, 0, stream>>>(bucket, meta, cnt2, sorted);

  // experts in f16 MFMA, routed (2/3 of dense FLOPs), both 8-phase 256x256
  k_expert_h8<<<dim3(MT256, H_DIM / 256, 2), 512, 0, stream>>>(
      xh, w1t, comb, eb1, sorted, meta, ehs);
  k_expert_o8<<<dim3(MT256, O_DIM / 256, 2), 512, 0, stream>>>(
      ehs, w2t, comb, eb2, sorted, meta, out);
}

// Round 13
// 717.638 us; speedup vs baseline: 1.0776x; 1.0193x over previous
//
#include <hip/hip_runtime.h>
#include <cstdint>
#include <cstddef>

#define B_ROWS 8192
#define D_DIM  1024
#define H_DIM  4096
#define O_DIM  1024
#define E_NUM  3
#define K2     (2 * H_DIM)          // per-slot K in expert GEMM2
#define MT256  34                   // worst-case 256-row m-tiles: 32 + 2 (256-pad per bucket)
#define SLOT_MAX (MT256 * 256)

typedef __attribute__((ext_vector_type(4))) float f4;
typedef __attribute__((ext_vector_type(8))) _Float16 half8;

__device__ __forceinline__ unsigned short f2h_bits(float f) {
  _Float16 h = (_Float16)f;
  return __builtin_bit_cast(unsigned short, h);
}

// async global->LDS, 16B per lane. LDS dest = wave-uniform base + lane*16.
__device__ __forceinline__ void async16(const void* g, void* l) {
  __builtin_amdgcn_global_load_lds(
      (const __attribute__((address_space(1))) unsigned int*)g,
      (__attribute__((address_space(3))) unsigned int*)l, 16, 0, 0);
}

// ---------------- cast x (fp32 -> f16), 8 elems/thread ----------------
__global__ __launch_bounds__(256) void k_cast_x(const float* __restrict__ in,
                                                unsigned short* __restrict__ out) {
  size_t i = (size_t)blockIdx.x * 256 + threadIdx.x;
  const f4* p = (const f4*)in;
  f4 a = p[2 * i], b = p[2 * i + 1];
  half8 h;
#pragma unroll
  for (int j = 0; j < 4; ++j) { h[j] = (_Float16)a[j]; h[4 + j] = (_Float16)b[j]; }
  *(half8*)(out + 8 * i) = h;
}

// ------------- transpose + cast: in[e][R][C] f32 -> out[e][C][R] f16 -------------
__global__ __launch_bounds__(256) void k_transpose_cast(const float* __restrict__ in,
                                                        unsigned short* __restrict__ out,
                                                        int R, int C) {
  __shared__ float tile[32][33];
  const size_t eoff = (size_t)blockIdx.z * R * C;
  const float* I = in + eoff;
  unsigned short* O = out + eoff;
  int c0 = blockIdx.x * 32, r0 = blockIdx.y * 32;
  int tx = threadIdx.x & 31, ty = threadIdx.x >> 5;
#pragma unroll
  for (int i = 0; i < 4; ++i)
    tile[ty + 8 * i][tx] = I[(size_t)(r0 + ty + 8 * i) * C + c0 + tx];
  __syncthreads();
#pragma unroll
  for (int i = 0; i < 4; ++i)
    O[(size_t)(c0 + ty + 8 * i) * R + r0 + tx] = f2h_bits(tile[tx][ty + 8 * i]);
}

// ------------- fp32 GEMM + bias + relu (gating layers), 64x64 tile -------------
__global__ __launch_bounds__(256) void k_gemm_f32(const float* __restrict__ A,
                                                  const float* __restrict__ Bm,
                                                  const float* __restrict__ bias,
                                                  float* __restrict__ C,
                                                  int N, int K) {
  __shared__ float sAT[16][68];
  __shared__ float sB[16][68];
  const int t = threadIdx.x;
  const int tx = t & 15, ty = t >> 4;
  const int m0 = blockIdx.y * 64, n0 = blockIdx.x * 64;
  float acc[4][4] = {};
  for (int k0 = 0; k0 < K; k0 += 16) {
    __syncthreads();
#pragma unroll
    for (int i = 0; i < 4; ++i) {
      int idx = t + i * 256;
      int r = idx >> 4, c = idx & 15;
      sAT[c][r] = A[(size_t)(m0 + r) * K + (k0 + c)];
      int rb = idx >> 6, cb = idx & 63;
      sB[rb][cb] = Bm[(size_t)(k0 + rb) * N + (n0 + cb)];
    }
    __syncthreads();
#pragma unroll
    for (int kk = 0; kk < 16; ++kk) {
      f4 av = *(const f4*)&sAT[kk][ty * 4];
      f4 bv = *(const f4*)&sB[kk][tx * 4];
#pragma unroll
      for (int i = 0; i < 4; ++i)
#pragma unroll
        for (int j = 0; j < 4; ++j)
          acc[i][j] = fmaf(av[i], bv[j], acc[i][j]);
    }
  }
#pragma unroll
  for (int i = 0; i < 4; ++i) {
    int row = m0 + ty * 4 + i;
    f4 v;
#pragma unroll
    for (int j = 0; j < 4; ++j)
      v[j] = fmaxf(acc[i][j] + bias[n0 + tx * 4 + j], 0.f);
    *(f4*)&C[(size_t)row * N + n0 + tx * 4] = v;
  }
}

// ------------- gating layer 3 + softmax + top-2 + renorm + bucket id -------------
__global__ __launch_bounds__(256) void k_gate_topk(const float* __restrict__ h2,
                                                   const float* __restrict__ gw3,
                                                   const float* __restrict__ gb3,
                                                   float* __restrict__ gates,
                                                   float* __restrict__ combine,
                                                   int* __restrict__ bucket) {
  const int lane = threadIdx.x & 63;
  const int row = blockIdx.x * 4 + (threadIdx.x >> 6);
  const float* h = h2 + (size_t)row * 128;
  float h0 = h[lane], h1 = h[lane + 64];
  float l0 = h0 * gw3[lane * 3 + 0] + h1 * gw3[(lane + 64) * 3 + 0];
  float l1 = h0 * gw3[lane * 3 + 1] + h1 * gw3[(lane + 64) * 3 + 1];
  float l2 = h0 * gw3[lane * 3 + 2] + h1 * gw3[(lane + 64) * 3 + 2];
#pragma unroll
  for (int off = 32; off > 0; off >>= 1) {
    l0 += __shfl_down(l0, off);
    l1 += __shfl_down(l1, off);
    l2 += __shfl_down(l2, off);
  }
  if (lane == 0) {
    float g0 = l0 + gb3[0], g1v = l1 + gb3[1], g2v = l2 + gb3[2];
    float mx = fmaxf(g0, fmaxf(g1v, g2v));
    float e0 = expf(g0 - mx), e1 = expf(g1v - mx), e2 = expf(g2v - mx);
    float inv = 1.f / (e0 + e1 + e2);
    float p0 = e0 * inv, p1 = e1 * inv, p2 = e2 * inv;
    gates[row * 3 + 0] = p0; gates[row * 3 + 1] = p1; gates[row * 3 + 2] = p2;
    // exclude argmin; '<=' so ties exclude the HIGHER index (lax.top_k tie rule)
    int amin = 0; float pm = p0;
    if (p1 <= pm) { pm = p1; amin = 1; }
    if (p2 <= pm) { pm = p2; amin = 2; }
    float denom = (p0 + p1 + p2) - pm;
    combine[row * 3 + 0] = (amin == 0) ? 0.f : p0 / denom;
    combine[row * 3 + 1] = (amin == 1) ? 0.f : p1 / denom;
    combine[row * 3 + 2] = (amin == 2) ? 0.f : p2 / denom;
    bucket[row] = amin;  // bucket = excluded expert
  }
}

// ------------- routing: count / bases / scatter (ballot-aggregated atomics) -------------
__global__ __launch_bounds__(256) void k_count(const int* __restrict__ bucket,
                                               int* __restrict__ cnt) {
  int row = blockIdx.x * 256 + threadIdx.x;
  int b = bucket[row];
  int lane = threadIdx.x & 63;
#pragma unroll
  for (int bid = 0; bid < 3; ++bid) {
    unsigned long long m = __ballot(b == bid);
    if (m && b == bid) {
      int prefix = __popcll(m & ((1ull << lane) - 1));
      if (prefix == 0) atomicAdd(&cnt[bid], __popcll(m));
    }
  }
}

// meta[0..3] = tile-base prefix in 256-row tiles (tiles_b = ceil(cnt_b/256)); zeroes cnt2.
__global__ void k_meta(const int* __restrict__ cnt, int* __restrict__ meta,
                       int* __restrict__ cnt2) {
  int t0 = (cnt[0] + 255) >> 8;
  int t1 = (cnt[1] + 255) >> 8;
  int t2 = (cnt[2] + 255) >> 8;
  meta[0] = 0; meta[1] = t0; meta[2] = t0 + t1; meta[3] = t0 + t1 + t2;
  cnt2[0] = 0; cnt2[1] = 0; cnt2[2] = 0;
}

__global__ __launch_bounds__(256) void k_scatter(const int* __restrict__ bucket,
                                                 const int* __restrict__ meta,
                                                 int* __restrict__ cnt2,
                                                 int* __restrict__ sorted) {
  int row = blockIdx.x * 256 + threadIdx.x;
  int b = bucket[row];
  int lane = threadIdx.x & 63;
#pragma unroll
  for (int bid = 0; bid < 3; ++bid) {
    unsigned long long m = __ballot(b == bid);
    if (m) {
      int cntm = __popcll(m);
      int leader = __ffsll((unsigned long long)m) - 1;
      int base = 0;
      if (lane == leader) base = atomicAdd(&cnt2[bid], cntm);
      base = __shfl(base, leader);
      if (b == bid) {
        int prefix = __popcll(m & ((1ull << lane) - 1));
        sorted[meta[bid] * 256 + base + prefix] = row;
      }
    }
  }
}

// experts for bucket b (b = excluded expert)
__device__ __forceinline__ void bucket_experts(int b, int& ea, int& eb) {
  ea = (b == 0) ? 1 : 0;
  eb = (b == 2) ? 1 : 2;
}

// ==================== 8-phase 256x256 schedule machinery (T3+T4+T5) ====================
// 512 threads = 8 waves (2M x 4N), wave tile 128x64, BK=64, 2 K-tiles/iteration.
// LDS: A dbuf 2x32KB + B dbuf 2x32KB = 128KB, XOR chunk swizzle.
// vmcnt(4) at end-P4 / end-P8 keep prefetch loads in flight across barriers.

#define BAR8()  do { __builtin_amdgcn_s_barrier(); __builtin_amdgcn_sched_barrier(0); } while (0)
#define LGKM0() do { asm volatile("s_waitcnt lgkmcnt(0)" ::: "memory"); __builtin_amdgcn_sched_barrier(0); } while (0)
#define VMW(n)  do { asm volatile("s_waitcnt vmcnt(" #n ")" ::: "memory"); __builtin_amdgcn_sched_barrier(0); } while (0)

#define STG_A(buf, h, kt) do { \
    async16(aptr[(h) * 2 + 0] + (size_t)(kt) * 64, smem + (buf) * 32768 + (h) * 16384 + t * 16); \
    async16(aptr[(h) * 2 + 1] + (size_t)(kt) * 64, smem + (buf) * 32768 + (h) * 16384 + 8192 + t * 16); \
  } while (0)
#define STG_B(buf, h, kt) do { \
    async16(bptr[(h) * 2 + 0] + (size_t)(kt) * 64, smem + 65536 + (buf) * 32768 + (h) * 16384 + t * 16); \
    async16(bptr[(h) * 2 + 1] + (size_t)(kt) * 64, smem + 65536 + (buf) * 32768 + (h) * 16384 + 8192 + t * 16); \
  } while (0)
#define LDA8(buf, mh) do { \
    _Pragma("unroll") \
    for (int mf = 0; mf < 4; ++mf) { \
      fa[mf][0] = *(const half8*)(smem + (buf) * 32768 + baseA + (mh) * 8192 + mf * 2048 + ck0); \
      fa[mf][1] = *(const half8*)(smem + (buf) * 32768 + baseA + (mh) * 8192 + mf * 2048 + ck1); \
    } } while (0)
#define LDB8(buf, nh) do { \
    _Pragma("unroll") \
    for (int nf2 = 0; nf2 < 2; ++nf2) { \
      fb[(nh) * 2 + nf2][0] = *(const half8*)(smem + (buf) * 32768 + baseB + ((nh) * 2 + nf2) * 2048 + ck0); \
      fb[(nh) * 2 + nf2][1] = *(const half8*)(smem + (buf) * 32768 + baseB + ((nh) * 2 + nf2) * 2048 + ck1); \
    } } while (0)
#define MM8(mh, nh) do { \
    _Pragma("unroll") \
    for (int mf = 0; mf < 4; ++mf) { \
      _Pragma("unroll") \
      for (int nf2 = 0; nf2 < 2; ++nf2) { \
        acc[(mh) * 4 + mf][(nh) * 2 + nf2] = __builtin_amdgcn_mfma_f32_16x16x32_f16( \
            fa[mf][0], fb[(nh) * 2 + nf2][0], acc[(mh) * 4 + mf][(nh) * 2 + nf2], 0, 0, 0); \
        acc[(mh) * 4 + mf][(nh) * 2 + nf2] = __builtin_amdgcn_mfma_f32_16x16x32_f16( \
            fa[mf][1], fb[(nh) * 2 + nf2][1], acc[(mh) * 4 + mf][(nh) * 2 + nf2], 0, 0, 0); \
      } } } while (0)

// Main pipelined K-loop: NITER iterations of 2 K-tiles; last kt index = 2*NITER-1.
#define KLOOP8(NITER, LASTKT) \
  _Pragma("unroll 1") \
  for (int it = 0; it < (NITER) - 1; ++it) { \
    const int kt = 2 * it; \
    LDA8(0, 0); LDB8(0, 0); STG_A(1, 0, kt + 1); \
    BAR8(); LGKM0(); \
    __builtin_amdgcn_s_setprio(1); MM8(0, 0); __builtin_amdgcn_s_setprio(0); \
    BAR8(); \
    LDB8(0, 1); STG_A(1, 1, kt + 1); \
    BAR8(); LGKM0(); \
    __builtin_amdgcn_s_setprio(1); MM8(0, 1); __builtin_amdgcn_s_setprio(0); \
    BAR8(); \
    LDA8(0, 1); STG_B(0, 0, kt + 2); \
    BAR8(); LGKM0(); \
    __builtin_amdgcn_s_setprio(1); MM8(1, 0); __builtin_amdgcn_s_setprio(0); \
    BAR8(); \
    STG_A(0, 0, kt + 2); \
    BAR8(); LGKM0(); \
    __builtin_amdgcn_s_setprio(1); MM8(1, 1); __builtin_amdgcn_s_setprio(0); \
    VMW(4); BAR8(); \
    LDA8(1, 0); LDB8(1, 0); STG_A(0, 1, kt + 2); \
    BAR8(); LGKM0(); \
    __builtin_amdgcn_s_setprio(1); MM8(0, 0); __builtin_amdgcn_s_setprio(0); \
    BAR8(); \
    LDB8(1, 1); STG_B(0, 1, kt + 2); \
    BAR8(); LGKM0(); \
    __builtin_amdgcn_s_setprio(1); MM8(0, 1); __builtin_amdgcn_s_setprio(0); \
    BAR8(); \
    LDA8(1, 1); STG_B(1, 0, kt + 3); \
    BAR8(); LGKM0(); \
    __builtin_amdgcn_s_setprio(1); MM8(1, 0); __builtin_amdgcn_s_setprio(0); \
    BAR8(); \
    STG_B(1, 1, kt + 3); \
    BAR8(); LGKM0(); \
    __builtin_amdgcn_s_setprio(1); MM8(1, 1); __builtin_amdgcn_s_setprio(0); \
    VMW(4); BAR8(); \
  } \
  { /* epilogue iteration: buf0 = kt LASTKT-1, stage buf1.A <- LASTKT, then buf1 */ \
    LDA8(0, 0); LDB8(0, 0); STG_A(1, 0, LASTKT); \
    BAR8(); LGKM0(); \
    __builtin_amdgcn_s_setprio(1); MM8(0, 0); __builtin_amdgcn_s_setprio(0); \
    BAR8(); \
    LDB8(0, 1); STG_A(1, 1, LASTKT); \
    BAR8(); LGKM0(); \
    __builtin_amdgcn_s_setprio(1); MM8(0, 1); __builtin_amdgcn_s_setprio(0); \
    BAR8(); \
    LDA8(0, 1); \
    BAR8(); LGKM0(); \
    __builtin_amdgcn_s_setprio(1); MM8(1, 0); __builtin_amdgcn_s_setprio(0); \
    BAR8(); \
    BAR8(); LGKM0(); \
    __builtin_amdgcn_s_setprio(1); MM8(1, 1); __builtin_amdgcn_s_setprio(0); \
    VMW(0); BAR8(); \
    LDA8(1, 0); LDB8(1, 0); MM8(0, 0); \
    LDB8(1, 1); MM8(0, 1); \
    LDA8(1, 1); MM8(1, 0); \
    MM8(1, 1); \
  }

// ==================== expert GEMM1 (routed), 8-phase 256x256 ====================
// ehs[slot][z*H + col] = f16(c * relu(x[r] @ w1_e + eb1_e))
// Epilogue stages the C-tile through the (dead) 128KB staging LDS as f16
// [256][256], then writes EHS in contiguous 16B chunks (512B runs per 32
// lanes) instead of 32 scattered 2B stores per thread. Values bit-identical.
__global__ __launch_bounds__(512, 2) void k_expert_h8(const unsigned short* __restrict__ Xh,
                                                      const unsigned short* __restrict__ W1T,
                                                      const float* __restrict__ combine,
                                                      const float* __restrict__ eb1,
                                                      const int* __restrict__ sorted,
                                                      const int* __restrict__ meta,
                                                      unsigned short* __restrict__ EHS) {
  constexpr int K = D_DIM;  // 1024, 16 K-tiles of 64, 8 iterations
  const int mt = blockIdx.x;
  const int tb1 = meta[1], tb2 = meta[2], tb3 = meta[3];
  if (mt >= tb3) return;
  const int b = (mt >= tb2) ? 2 : (mt >= tb1) ? 1 : 0;
  int ea, ebx; bucket_experts(b, ea, ebx);
  const int z = blockIdx.z;
  const int e = z ? ebx : ea;
  const int slot0 = mt * 256;
  const int n0 = blockIdx.y * 256;

  __shared__ __align__(16) char smem[131072];
  __shared__ float sC[256];
  const int t = threadIdx.x;
  if (t < 256) {
    int r = sorted[slot0 + t];
    sC[t] = (r < 0) ? 0.f : combine[(size_t)r * 3 + e];
  }

  // staging: 4 rows per thread (R = (t>>3) + i*64), pre-swizzled global chunk
  const int jrow = t >> 3;
  const int j = (t & 7) ^ (jrow & 7);
  const unsigned short* aptr[4];
  const unsigned short* bptr[4];
#pragma unroll
  for (int i = 0; i < 4; ++i) {
    int R = jrow + i * 64;
    int r = sorted[slot0 + R];
    int rr = (r < 0) ? 0 : r;
    aptr[i] = Xh + (size_t)rr * K + j * 8;
    bptr[i] = W1T + (size_t)e * H_DIM * K + (size_t)(n0 + R) * K + j * 8;
  }
  const int lane = t & 63;
  const int wid = t >> 6;
  const int wm = wid >> 2, wn = wid & 3;
  const int quad = lane >> 4, l16 = lane & 15;
  const int ck0 = ((quad) ^ (l16 & 7)) * 16;        // k-slice 0 chunk (swizzled)
  const int ck1 = ((4 + quad) ^ (l16 & 7)) * 16;    // k-slice 1 chunk
  const int baseA = (wm * 128 + l16) * 128;
  const int baseB = 65536 + (wn * 64 + l16) * 128;

  f4 acc[8][4] = {};
  half8 fa[4][2], fb[4][2];

  // prologue: buf0 <- kt0 (A+B), buf1.B <- kt1 (buf1.A staged by it0's P1/P2)
  STG_A(0, 0, 0); STG_A(0, 1, 0); STG_B(0, 0, 0); STG_B(0, 1, 0);
  STG_B(1, 0, 1); STG_B(1, 1, 1);
  VMW(4); BAR8();

  KLOOP8(8, 15)

  // ---- coalesced epilogue: C -> LDS f16 [256][256] -> 16B global chunks ----
  __syncthreads();   // all waves done reading buf1 before smem reuse
  unsigned short* cst = (unsigned short*)smem;   // 128 KB, fits in 131072
  const float* bias = eb1 + (size_t)e * H_DIM;
#pragma unroll
  for (int nf = 0; nf < 4; ++nf) {
    int colL = wn * 64 + nf * 16 + l16;
    float bb = bias[n0 + colL];
#pragma unroll
    for (int mf = 0; mf < 8; ++mf) {
#pragma unroll
      for (int r = 0; r < 4; ++r) {
        int rloc = wm * 128 + mf * 16 + quad * 4 + r;
        float v = fmaxf(acc[mf][nf][r] + bb, 0.f) * sC[rloc];
        cst[rloc * 256 + colL] = f2h_bits(v);
      }
    }
  }
  __syncthreads();
  // 8192 chunks of 16B (256 rows x 32 chunks), 512 threads x 16
#pragma unroll
  for (int i = 0; i < 16; ++i) {
    int c = t + i * 512;
    int row = c >> 5;
    int off = (c & 31) * 8;
    *(half8*)(EHS + (size_t)(slot0 + row) * K2 + (size_t)z * H_DIM + n0 + off) =
        *(const half8*)(cst + row * 256 + off);
  }
}

// ======= expert GEMM2 (routed, split-K by expert half), 8-phase 256x256 =======
// OUT += ehs[slot, half] @ w2_e   (hz=0 adds both bias terms; OUT pre-zeroed;
// f32 atomicAdds commute -> deterministic; split-2 = 17M atomics, r3-validated).
__global__ __launch_bounds__(512, 2) void k_expert_o8(const unsigned short* __restrict__ EHS,
                                                      const unsigned short* __restrict__ W2T,
                                                      const float* __restrict__ combine,
                                                      const float* __restrict__ eb2,
                                                      const int* __restrict__ sorted,
                                                      const int* __restrict__ meta,
                                                      float* __restrict__ OUT) {
  const int mt = blockIdx.x;
  const int tb1 = meta[1], tb2 = meta[2], tb3 = meta[3];
  if (mt >= tb3) return;
  const int b = (mt >= tb2) ? 2 : (mt >= tb1) ? 1 : 0;
  int ea, ebx; bucket_experts(b, ea, ebx);
  const int hz = blockIdx.z;
  const int e = hz ? ebx : ea;
  const int slot0 = mt * 256;
  const int n0 = blockIdx.y * 256;

  __shared__ __align__(16) char smem[131072];
  __shared__ int sRow[256];
  __shared__ float sCa[256], sCb[256];
  const int t = threadIdx.x;
  if (t < 256) {
    int r = sorted[slot0 + t];
    sRow[t] = r;
    int rr = (r < 0) ? 0 : r;
    sCa[t] = combine[(size_t)rr * 3 + ea];
    sCb[t] = combine[(size_t)rr * 3 + ebx];
  }

  // staging: 4 rows per thread (R = (t>>3) + i*64), pre-swizzled global chunk
  const int jrow = t >> 3;
  const int j = (t & 7) ^ (jrow & 7);
  const unsigned short* aptr[4];
  const unsigned short* bptr[4];
#pragma unroll
  for (int i = 0; i < 4; ++i) {
    int R = jrow + i * 64;
    aptr[i] = EHS + (size_t)(slot0 + R) * K2 + (size_t)hz * H_DIM + j * 8;
    bptr[i] = W2T + (size_t)e * O_DIM * H_DIM + (size_t)(n0 + R) * H_DIM + j * 8;
  }
  const int lane = t & 63;
  const int wid = t >> 6;
  const int wm = wid >> 2, wn = wid & 3;
  const int quad = lane >> 4, l16 = lane & 15;
  const int ck0 = ((quad) ^ (l16 & 7)) * 16;
  const int ck1 = ((4 + quad) ^ (l16 & 7)) * 16;
  const int baseA = (wm * 128 + l16) * 128;
  const int baseB = 65536 + (wn * 64 + l16) * 128;

  f4 acc[8][4] = {};
  half8 fa[4][2], fb[4][2];

  // prologue
  STG_A(0, 0, 0); STG_A(0, 1, 0); STG_B(0, 0, 0); STG_B(0, 1, 0);
  STG_B(1, 0, 1); STG_B(1, 1, 1);
  VMW(4); BAR8();

  // K = 4096 per half: 64 K-tiles of 64 -> 32 iterations, last kt = 63
  KLOOP8(32, 63)

#pragma unroll
  for (int nf = 0; nf < 4; ++nf) {
    int col = n0 + wn * 64 + nf * 16 + l16;
    float ba = eb2[(size_t)ea * O_DIM + col];
    float bb = eb2[(size_t)ebx * O_DIM + col];
#pragma unroll
    for (int mf = 0; mf < 8; ++mf) {
#pragma unroll
      for (int r = 0; r < 4; ++r) {
        int rloc = wm * 128 + mf * 16 + quad * 4 + r;
        int rowg = sRow[rloc];
        if (rowg >= 0) {
          float v = acc[mf][nf][r];
          if (hz == 0) v += sCa[rloc] * ba + sCb[rloc] * bb;
          atomicAdd(&OUT[(size_t)rowg * O_DIM + col], v);
        }
      }
    }
  }
}

extern "C" void kernel_launch(void* const* d_in, const int* in_sizes, int n_in,
                              void* d_out, int out_size, void* d_ws, size_t ws_size,
                              hipStream_t stream) {
  const float* x   = (const float*)d_in[0];
  const float* gw1 = (const float*)d_in[1];
  const float* gb1 = (const float*)d_in[2];
  const float* gw2 = (const float*)d_in[3];
  const float* gb2 = (const float*)d_in[4];
  const float* gw3 = (const float*)d_in[5];
  const float* gb3 = (const float*)d_in[6];
  const float* ew1 = (const float*)d_in[7];
  const float* eb1 = (const float*)d_in[8];
  const float* ew2 = (const float*)d_in[9];
  const float* eb2 = (const float*)d_in[10];
  float* out = (float*)d_out;
  float* gates = out + (size_t)B_ROWS * O_DIM;

  char* ws = (char*)d_ws;
  size_t off = 0;
  auto take = [&](size_t bytes) -> char* {
    char* p = ws + off;
    off += (bytes + 255) & ~(size_t)255;
    return p;
  };
  unsigned short* xh  = (unsigned short*)take((size_t)B_ROWS * D_DIM * 2);        // 16.8 MB
  unsigned short* w1t = (unsigned short*)take((size_t)E_NUM * H_DIM * D_DIM * 2); // 25.2 MB
  unsigned short* w2t = (unsigned short*)take((size_t)E_NUM * O_DIM * H_DIM * 2); // 25.2 MB
  float* comb   = (float*)take((size_t)B_ROWS * 3 * 4);
  float* g1     = (float*)take((size_t)B_ROWS * 256 * 4);                         // 8.4 MB
  float* h2     = (float*)take((size_t)B_ROWS * 128 * 4);                         // 4.2 MB
  int* bucket   = (int*)take((size_t)B_ROWS * 4);
  int* sorted   = (int*)take((size_t)SLOT_MAX * 4);
  int* cnt      = (int*)take(3 * 4);
  int* cnt2     = (int*)take(3 * 4);
  int* meta     = (int*)take(4 * 4);
  unsigned short* ehs = (unsigned short*)take((size_t)SLOT_MAX * K2 * 2);         // 142.6 MB

  hipMemsetAsync(cnt, 0, 3 * 4, stream);
  hipMemsetAsync(sorted, 0xFF, (size_t)SLOT_MAX * 4, stream);  // pad slots = -1
  hipMemsetAsync(out, 0, (size_t)B_ROWS * O_DIM * 4, stream);  // accumulate base for split-K

  // precision-insensitive pre-pass: f16 casts/transposes
  k_cast_x<<<dim3(B_ROWS * D_DIM / (256 * 8)), 256, 0, stream>>>(x, xh);
  k_transpose_cast<<<dim3(H_DIM / 32, D_DIM / 32, E_NUM), 256, 0, stream>>>(ew1, w1t, D_DIM, H_DIM);
  k_transpose_cast<<<dim3(O_DIM / 32, H_DIM / 32, E_NUM), 256, 0, stream>>>(ew2, w2t, H_DIM, O_DIM);

  // gating in fp32 (top-k selection must track the fp32 reference)
  k_gemm_f32<<<dim3(256 / 64, B_ROWS / 64), 256, 0, stream>>>(x, gw1, gb1, g1, 256, D_DIM);
  k_gemm_f32<<<dim3(128 / 64, B_ROWS / 64), 256, 0, stream>>>(g1, gw2, gb2, h2, 128, 256);
  k_gate_topk<<<dim3(B_ROWS / 4), 256, 0, stream>>>(h2, gw3, gb3, gates, comb, bucket);

  // routing: bucket rows by excluded expert into 256-aligned sorted segments
  k_count<<<dim3(B_ROWS / 256), 256, 0, stream>>>(bucket, cnt);
  k_meta<<<1, 1, 0, stream>>>(cnt, meta, cnt2);
  k_scatter<<<dim3(B_ROWS / 256), 256, 0, stream>>>(bucket, meta, cnt2, sorted);

  // experts in f16 MFMA, routed (2/3 of dense FLOPs), both 8-phase 256x256
  k_expert_h8<<<dim3(MT256, H_DIM / 256, 2), 512, 0, stream>>>(
      xh, w1t, comb, eb1, sorted, meta, ehs);
  k_expert_o8<<<dim3(MT256, O_DIM / 256, 2), 512, 0, stream>>>(
      ehs, w2t, comb, eb2, sorted, meta, out);
}